// Round 16
// baseline (515.790 us; speedup 1.0000x reference)
//
#include <hip/hip_runtime.h>
#include <math.h>

// ---------------------------------------------------------------------------
// VQ-VAE forward. R29 = R28 + convf one-row-per-thread (512 thr):
//  - R28 fixed traffic (FETCH 405->93MB) but exposed latency: 43.5KB LDS ->
//    3 blk/CU x 4 waves = 12 waves/CU (30% occ), 48-deep predicated chain,
//    125.6us with all pipes <25%.
//  - R29: 512 threads, 1 output row/thread (500 active), guard-free inner
//    loop (3 dx x 3 lr x 4 i4v = 36 LDS reads); 8 waves/blk x 3 blk/CU =
//    24 waves/CU (75%). Weights stay wave-uniform (SGPR). Same staging.
//  conv1: x -> h1 split-bf16 (n,25,25,[hi32|lo32])   [regA]
//  enc_m: h1 -> z split-bf16 (n,13,13,[zh64|zl64])   [regB]
//  vq_m:  z -> q bf16 [regA] + lpart (no atomics)
//  tconv1 MFMA: q -> d1 (n,25,25,64) bf16            [regB]
//  tconv2 MFMA: d1 -> d2 (n,50,50,32) bf16           [regA]
//  convf LDS-strip 512thr k3s1p1+sigm -> out (n,50,50)
// ---------------------------------------------------------------------------

typedef __attribute__((ext_vector_type(8))) short s8v;   // 8 bf16 frag
typedef __attribute__((ext_vector_type(4))) float f4v;   // MFMA acc
typedef __attribute__((ext_vector_type(4))) int i4v;
typedef __attribute__((ext_vector_type(4))) short s4v;
typedef __attribute__((ext_vector_type(2))) float f2v;   // packed f32 pair

__device__ inline unsigned short f2bf(float f) {  // RNE fp32->bf16
    unsigned u = __builtin_bit_cast(unsigned, f);
    return (unsigned short)((u + 0x7fffu + ((u >> 16) & 1u)) >> 16);
}
__device__ inline float bf2f(unsigned short h) {
    return __builtin_bit_cast(float, ((unsigned)h) << 16);
}

// ---- fused prep: cbm | B2n | B1 | B2 | B3 | cn | loss-zero | wpk -----------
__global__ __launch_bounds__(256) void k_prep_all(
        const float* __restrict__ cb,  const float* __restrict__ ew2,
        const float* __restrict__ ew3, const float* __restrict__ dw1,
        const float* __restrict__ dw2, const float* __restrict__ dw3,
        unsigned short* __restrict__ cbm, unsigned short* __restrict__ wB2n,
        unsigned short* __restrict__ wB1, unsigned short* __restrict__ wB2,
        unsigned short* __restrict__ wB3, float* __restrict__ cn,
        float* __restrict__ loss, f2v* __restrict__ wpk) {
    int i = blockIdx.x * 256 + threadIdx.x;
    if (i < 98304) {
        // cbm: VQ codebook 3-product split (nt32, kc6, lane64, j8)
        int j = i & 7, lane = (i >> 3) & 63;
        int kc = (i >> 9) % 6, nt = (i >> 9) / 6;
        int n = nt * 16 + (lane & 15);
        int k = kc * 32 + ((lane >> 4) << 3) + j;
        int seg = k >> 6, kk = k & 63;
        float c = cb[n * 64 + kk];
        unsigned short ch = f2bf(c);
        cbm[i] = (seg == 1) ? f2bf(c - bf2f(ch)) : ch;
    } else if (i < 153600) {
        // B2n: conv2 split (nt4, kc27, lane64, j8); K1=864 = [hi288|lo288|hi288]
        int q = i - 98304;
        int j = q & 7, lane = (q >> 3) & 63;
        int kc = (q >> 9) % 27, nt = (q >> 9) / 27;
        int k = kc * 32 + ((lane >> 4) << 3) + j;
        int co = nt * 16 + (lane & 15);
        int part = (k < 288) ? 0 : (k < 576) ? 1 : 0;
        int kk = (k < 288) ? k : (k < 576) ? k - 288 : k - 576;
        int tap = kk >> 5, ci = kk & 31;
        float v = ew2[(co * 32 + ci) * 9 + tap];
        unsigned short hi = f2bf(v);
        wB2n[q] = part ? f2bf(v - bf2f(hi)) : hi;
    } else if (i < 219136) {
        // B1: tconv1 zero-padded (nt16, kc8, lane64, j8)
        int q = i - 153600;
        int j = q & 7, l = (q >> 3) & 63, kc = (q >> 9) & 7, nt = q >> 12;
        int n = nt * 16 + (l & 15), k = kc * 32 + (l >> 4) * 8 + j;
        int cls = n >> 6, co = n & 63, p = k >> 6, ci = k & 63;
        int jh = -1, jw = -1;
        if (cls == 0)      { if (p == 0) { jh = 1; jw = 1; } }
        else if (cls == 1) { if (p == 1) { jh = 1; jw = 0; } else if (p == 0) { jh = 1; jw = 2; } }
        else if (cls == 2) { if (p == 2) { jh = 0; jw = 1; } else if (p == 0) { jh = 2; jw = 1; } }
        else { if (p == 3) { jh = 0; jw = 0; } else if (p == 2) { jh = 0; jw = 2; }
               else if (p == 1) { jh = 2; jw = 0; } else { jh = 2; jw = 2; } }
        float v = (jh >= 0) ? dw1[((co * 64 + ci) * 3 + jh) * 3 + jw] : 0.f;
        wB1[q] = f2bf(v);
    } else if (i < 251904) {
        // B2: tconv2 zero-padded (nt8, kc8, lane64, j8)
        int q = i - 219136;
        int j = q & 7, l = (q >> 3) & 63, kc = (q >> 9) & 7, nt = q >> 12;
        int n = nt * 16 + (l & 15), k = kc * 32 + (l >> 4) * 8 + j;
        int cls = n >> 5, co = n & 31, p = k >> 6, ci = k & 63;
        int jh = -1, jw = -1;
        if (cls == 0)      { if (p == 0) { jh = 1; jw = 1; } }
        else if (cls == 1) { if (p == 1) { jh = 1; jw = 0; } else if (p == 0) { jh = 1; jw = 2; } }
        else if (cls == 2) { if (p == 2) { jh = 0; jw = 1; } else if (p == 0) { jh = 2; jw = 1; } }
        else { if (p == 3) { jh = 0; jw = 0; } else if (p == 2) { jh = 0; jw = 2; }
               else if (p == 1) { jh = 2; jw = 0; } else { jh = 2; jw = 2; } }
        float v = (jh >= 0) ? dw2[((co * 64 + ci) * 3 + jh) * 3 + jw] : 0.f;
        wB2[q] = f2bf(v);
    } else if (i < 264192) {
        // B3: conv3 split (nt4, kc6, lane64, j8); K2=192 = [hi64|lo64|hi64]
        int q = i - 251904;
        int j = q & 7, lane = (q >> 3) & 63;
        int kc = (q >> 9) % 6, nt = (q >> 9) / 6;
        int k = kc * 32 + ((lane >> 4) << 3) + j;
        int n = nt * 16 + (lane & 15);
        int part = (k < 64) ? 0 : (k < 128) ? 1 : 0;
        int kk = (k < 64) ? k : (k < 128) ? k - 64 : k - 128;
        float v = ew3[n * 64 + kk];
        unsigned short hi = f2bf(v);
        wB3[q] = part ? f2bf(v - bf2f(hi)) : hi;
    } else if (i < 264704) {
        int k = i - 264192;
        const float* r = cb + k * 64;
        float s = 0.f;
#pragma unroll
        for (int c = 0; c < 64; ++c) s += r[c] * r[c];
        cn[k] = s;
    } else if (i == 264704) {
        *loss = 0.f;
    } else if (i < 264849) {
        // wpk: convf weights packed per channel-pair: wpk[(kw*3+kh)*16+ii]
        int q = i - 264705;
        int kw = q / 48, rem = q % 48, kh = rem / 16, ii = rem % 16;
        f2v w;
        w[0] = dw3[(2 * ii) * 9 + kh * 3 + kw];
        w[1] = dw3[(2 * ii + 1) * 9 + kh * 3 + kw];
        wpk[q] = w;
    }
}

// ---- conv1: x (bc,50,50) -> h1 split-bf16 (bc,25,25,[hi32|lo32]), relu -----
__global__ __launch_bounds__(256) void k_conv1(const float* __restrict__ x,
                                               const float* __restrict__ w,
                                               const float* __restrict__ b,
                                               unsigned short* __restrict__ h1,
                                               int total) {
    __shared__ float4 wl4[72];
    float* wl = (float*)wl4;
    int tid = threadIdx.x;
    for (int t = tid; t < 288; t += 256) {
        int tap = t >> 5, co = t & 31;
        wl[t] = w[co * 9 + tap];
    }
    __syncthreads();
    int pix = blockIdx.x * 256 + tid;
    if (pix >= total) return;
    int n = pix / 625, p = pix % 625, oh = p / 25, ow = p % 25;
    const float* xp = x + (size_t)n * 2500;
    float4 a[8];
#pragma unroll
    for (int j = 0; j < 8; ++j) a[j] = ((const float4*)b)[j];
#pragma unroll
    for (int kh = 0; kh < 3; ++kh) {
        int ih = 2 * oh - 1 + kh;
        if ((unsigned)ih >= 50u) continue;
#pragma unroll
        for (int kw = 0; kw < 3; ++kw) {
            int iw = 2 * ow - 1 + kw;
            if ((unsigned)iw >= 50u) continue;
            float v = xp[ih * 50 + iw];
            int tap = kh * 3 + kw;
#pragma unroll
            for (int j = 0; j < 8; ++j) {
                float4 ww = wl4[tap * 8 + j];
                a[j].x += v * ww.x; a[j].y += v * ww.y;
                a[j].z += v * ww.z; a[j].w += v * ww.w;
            }
        }
    }
    // relu + split-pack: [hi 32ch | lo 32ch] = 128 B/pixel (same bytes as f32)
    unsigned short hi[32], lo[32];
#pragma unroll
    for (int j = 0; j < 8; ++j) {
        float vv[4] = {a[j].x, a[j].y, a[j].z, a[j].w};
#pragma unroll
        for (int e = 0; e < 4; ++e) {
            float v = fmaxf(vv[e], 0.f);
            unsigned short h = f2bf(v);
            hi[j * 4 + e] = h;
            lo[j * 4 + e] = f2bf(v - bf2f(h));
        }
    }
    i4v* op = (i4v*)(h1 + (size_t)pix * 64);
#pragma unroll
    for (int g = 0; g < 4; ++g) {
        i4v ph, pl;
#pragma unroll
        for (int e = 0; e < 4; ++e) {
            int b0 = g * 8 + e * 2;
            ph[e] = (int)((unsigned)hi[b0] | ((unsigned)hi[b0 + 1] << 16));
            pl[e] = (int)((unsigned)lo[b0] | ((unsigned)lo[b0 + 1] << 16));
        }
        op[g] = ph;
        op[4 + g] = pl;
    }
}

// ---- enc_m: fused conv2(k3s2p1)+relu+conv3(1x1), split-bf16 MFMA (M=16) ----
// a1 deduped [hi 9x40 | lo 9x40] (row 728); A-frags register-resident.
__global__ __launch_bounds__(256, 2) void k_enc_m(const unsigned short* __restrict__ h1,
                                                  const unsigned short* __restrict__ B2n,
                                                  const unsigned short* __restrict__ B3,
                                                  const float* __restrict__ b2,
                                                  const float* __restrict__ b3,
                                                  unsigned short* __restrict__ z, int npix) {
    __shared__ short a1[16 * 728];   // [m16][seg2: hi|lo][tap9][40(32+8pad)]
    __shared__ short a2[16 * 136];   // [m16][zh64|zl64|pad8]
    __shared__ short czs[16 * 136];
    int tid = threadIdx.x, blk = blockIdx.x;
    // staging: u = (m*18 + (seg*9+t))*4 + sub; consecutive lanes ->
    // consecutive 16B LDS writes (conflict-free). 1152 slots, 5 passes.
#pragma unroll
    for (int pass = 0; pass < 5; ++pass) {
        int u = tid + pass * 256;
        if (u < 1152) {
            int m = u / 72, rem = u - m * 72;
            int idx = rem >> 2, sub = rem & 3;
            int seg = (idx >= 9) ? 1 : 0;
            int t = idx - seg * 9;
            i4v v = (i4v){0, 0, 0, 0};
            int pix = blk * 16 + m;
            if (pix < npix) {
                int n = pix / 169, p = pix % 169, oh = p / 13, ow = p % 13;
                int ih = 2 * oh - 1 + t / 3, iw = 2 * ow - 1 + t % 3;
                if (((unsigned)ih < 25u) && ((unsigned)iw < 25u))
                    v = *(const i4v*)(h1 + (((size_t)n * 25 + ih) * 25 + iw) * 64
                                      + (seg * 4 + sub) * 8);
            }
            *(i4v*)(a1 + m * 728 + seg * 360 + t * 40 + sub * 8) = v;
        }
    }
    __syncthreads();
    int wave = tid >> 6, lane = tid & 63;
    int r = lane & 15, g = lane >> 4;
    // A-fragments register-resident: 9 hi + 9 lo (72 VGPR)
    int abase = r * 728 + g * 8;
    s8v ah[9], al[9];
#pragma unroll
    for (int t = 0; t < 9; ++t) {
        ah[t] = *(const s8v*)(a1 + abase + t * 40);
        al[t] = *(const s8v*)(a1 + abase + 360 + t * 40);
    }
    f4v acc = (f4v){0.f, 0.f, 0.f, 0.f};
    // K=864 = [ah x wh (taps 0-8) | ah x wl | al x wh]
#pragma unroll
    for (int kc = 0; kc < 27; ++kc) {
        s8v b = *(const s8v*)((const short*)B2n + ((size_t)((wave * 27 + kc) * 64 + lane)) * 8);
        s8v a = (kc < 9) ? ah[kc] : (kc < 18) ? ah[kc - 9] : al[kc - 18];
        acc = __builtin_amdgcn_mfma_f32_16x16x32_bf16(a, b, acc, 0, 0, 0);
    }
    {
        float bv = b2[wave * 16 + r];
        int n = wave * 16 + r;
#pragma unroll
        for (int rr = 0; rr < 4; ++rr) {
            int m = g * 4 + rr;
            float h = fmaxf(acc[rr] + bv, 0.f);
            unsigned short hh = f2bf(h);
            a2[m * 136 + n] = (short)hh;
            a2[m * 136 + 64 + n] = (short)f2bf(h - bf2f(hh));
        }
    }
    __syncthreads();
    // conv3: 4 reg frags feed 6 MFMAs; B3 = [ch|cl|ch], A = [zh|zh|zl]
    int arow2 = r * 136 + g * 8;
    s8v zh0 = *(const s8v*)(a2 + arow2);
    s8v zh1 = *(const s8v*)(a2 + arow2 + 32);
    s8v zl0 = *(const s8v*)(a2 + arow2 + 64);
    s8v zl1 = *(const s8v*)(a2 + arow2 + 96);
    f4v acc2 = (f4v){0.f, 0.f, 0.f, 0.f};
    {
        const short* bp3 = (const short*)B3 + ((size_t)(wave * 6 * 64 + lane)) * 8;
        s8v b0 = *(const s8v*)(bp3);
        s8v b1 = *(const s8v*)(bp3 + 64 * 8);
        s8v b2f = *(const s8v*)(bp3 + 2 * 64 * 8);
        s8v b3f = *(const s8v*)(bp3 + 3 * 64 * 8);
        s8v b4 = *(const s8v*)(bp3 + 4 * 64 * 8);
        s8v b5 = *(const s8v*)(bp3 + 5 * 64 * 8);
        acc2 = __builtin_amdgcn_mfma_f32_16x16x32_bf16(zh0, b0, acc2, 0, 0, 0);
        acc2 = __builtin_amdgcn_mfma_f32_16x16x32_bf16(zh1, b1, acc2, 0, 0, 0);
        acc2 = __builtin_amdgcn_mfma_f32_16x16x32_bf16(zh0, b2f, acc2, 0, 0, 0);
        acc2 = __builtin_amdgcn_mfma_f32_16x16x32_bf16(zh1, b3f, acc2, 0, 0, 0);
        acc2 = __builtin_amdgcn_mfma_f32_16x16x32_bf16(zl0, b4, acc2, 0, 0, 0);
        acc2 = __builtin_amdgcn_mfma_f32_16x16x32_bf16(zl1, b5, acc2, 0, 0, 0);
    }
    {
        // emit z pre-split: [zh 64ch | zl 64ch] = 256 B/pixel (same bytes as f32)
        float bv = b3[wave * 16 + r];
        int n = wave * 16 + r;
#pragma unroll
        for (int rr = 0; rr < 4; ++rr) {
            int m = g * 4 + rr;
            float v = acc2[rr] + bv;
            unsigned short hh = f2bf(v);
            czs[m * 136 + n] = (short)hh;
            czs[m * 136 + 64 + n] = (short)f2bf(v - bf2f(hh));
        }
    }
    __syncthreads();
    {
        int m = tid >> 4, t = tid & 15;
        int pix = blk * 16 + m;
        if (pix < npix)
            *(i4v*)(z + (size_t)pix * 128 + t * 8) = *(i4v*)(czs + m * 136 + t * 8);
    }
}

// ---- vq_m: M=128/block, wave-local 512-code scan, loss partial store -------
__global__ __launch_bounds__(256, 2) void k_vq_m(const unsigned short* __restrict__ z,
                                                 const float* __restrict__ cb,
                                                 const unsigned short* __restrict__ cbm,
                                                 const float* __restrict__ cn,
                                                 unsigned short* __restrict__ q,
                                                 float* __restrict__ lpart, int npix) {
    __shared__ short a_lds[128 * 136];
    __shared__ int bkf[128];
    __shared__ float lred4[4];
    int tid = threadIdx.x, blk = blockIdx.x;
    {
        const i4v* src = (const i4v*)(z + (size_t)blk * 128 * 128);
#pragma unroll
        for (int it = 0; it < 8; ++it) {
            int L = it * 256 + tid;
            int m = L >> 4, s = L & 15;
            int pix = blk * 128 + m;
            i4v v = (i4v){0, 0, 0, 0};
            if (pix < npix) v = src[L];
            *(i4v*)(a_lds + m * 136 + s * 8) = v;
        }
    }
    __syncthreads();
    int wave = tid >> 6, lane = tid & 63;
    int arow0 = (wave * 32 + (lane & 15)) * 136 + (lane >> 4) * 8;
    int arow1 = arow0 + 16 * 136;
    s8v af00 = *(const s8v*)(a_lds + arow0);
    s8v af01 = *(const s8v*)(a_lds + arow0 + 32);
    s8v af02 = *(const s8v*)(a_lds + arow0 + 64);
    s8v af03 = *(const s8v*)(a_lds + arow0 + 96);
    s8v af10 = *(const s8v*)(a_lds + arow1);
    s8v af11 = *(const s8v*)(a_lds + arow1 + 32);
    s8v af12 = *(const s8v*)(a_lds + arow1 + 64);
    s8v af13 = *(const s8v*)(a_lds + arow1 + 96);
    float bd0[4], bd1[4];
    int bk0[4], bk1[4];
#pragma unroll
    for (int r = 0; r < 4; ++r) {
        bd0[r] = 3.4e38f; bk0[r] = 0;
        bd1[r] = 3.4e38f; bk1[r] = 0;
    }
    const s8v* bp = (const s8v*)cbm + lane;
    int ln15 = lane & 15;
    s8v bfA[6], bfB[6];
#pragma unroll
    for (int kc = 0; kc < 6; ++kc) bfA[kc] = bp[kc * 64];
    float cnA = cn[ln15];
    float cnB;
    for (int nt = 0; nt < 32; nt += 2) {
#pragma unroll
        for (int kc = 0; kc < 6; ++kc) bfB[kc] = bp[((nt + 1) * 6 + kc) * 64];
        cnB = cn[(nt + 1) * 16 + ln15];
        {
            f4v acc0 = (f4v){0.f, 0.f, 0.f, 0.f};
            f4v acc1 = (f4v){0.f, 0.f, 0.f, 0.f};
            acc0 = __builtin_amdgcn_mfma_f32_16x16x32_bf16(af00, bfA[0], acc0, 0, 0, 0);
            acc1 = __builtin_amdgcn_mfma_f32_16x16x32_bf16(af10, bfA[0], acc1, 0, 0, 0);
            acc0 = __builtin_amdgcn_mfma_f32_16x16x32_bf16(af01, bfA[1], acc0, 0, 0, 0);
            acc1 = __builtin_amdgcn_mfma_f32_16x16x32_bf16(af11, bfA[1], acc1, 0, 0, 0);
            acc0 = __builtin_amdgcn_mfma_f32_16x16x32_bf16(af00, bfA[2], acc0, 0, 0, 0);
            acc1 = __builtin_amdgcn_mfma_f32_16x16x32_bf16(af10, bfA[2], acc1, 0, 0, 0);
            acc0 = __builtin_amdgcn_mfma_f32_16x16x32_bf16(af01, bfA[3], acc0, 0, 0, 0);
            acc1 = __builtin_amdgcn_mfma_f32_16x16x32_bf16(af11, bfA[3], acc1, 0, 0, 0);
            acc0 = __builtin_amdgcn_mfma_f32_16x16x32_bf16(af02, bfA[4], acc0, 0, 0, 0);
            acc1 = __builtin_amdgcn_mfma_f32_16x16x32_bf16(af12, bfA[4], acc1, 0, 0, 0);
            acc0 = __builtin_amdgcn_mfma_f32_16x16x32_bf16(af03, bfA[5], acc0, 0, 0, 0);
            acc1 = __builtin_amdgcn_mfma_f32_16x16x32_bf16(af13, bfA[5], acc1, 0, 0, 0);
            int kcol = nt * 16 + ln15;
#pragma unroll
            for (int r = 0; r < 4; ++r) {
                float d0 = cnA - 2.f * acc0[r];
                if (d0 < bd0[r]) { bd0[r] = d0; bk0[r] = kcol; }
                float d1 = cnA - 2.f * acc1[r];
                if (d1 < bd1[r]) { bd1[r] = d1; bk1[r] = kcol; }
            }
        }
        if (nt + 2 < 32) {
#pragma unroll
            for (int kc = 0; kc < 6; ++kc) bfA[kc] = bp[((nt + 2) * 6 + kc) * 64];
            cnA = cn[(nt + 2) * 16 + ln15];
        }
        {
            f4v acc0 = (f4v){0.f, 0.f, 0.f, 0.f};
            f4v acc1 = (f4v){0.f, 0.f, 0.f, 0.f};
            acc0 = __builtin_amdgcn_mfma_f32_16x16x32_bf16(af00, bfB[0], acc0, 0, 0, 0);
            acc1 = __builtin_amdgcn_mfma_f32_16x16x32_bf16(af10, bfB[0], acc1, 0, 0, 0);
            acc0 = __builtin_amdgcn_mfma_f32_16x16x32_bf16(af01, bfB[1], acc0, 0, 0, 0);
            acc1 = __builtin_amdgcn_mfma_f32_16x16x32_bf16(af11, bfB[1], acc1, 0, 0, 0);
            acc0 = __builtin_amdgcn_mfma_f32_16x16x32_bf16(af00, bfB[2], acc0, 0, 0, 0);
            acc1 = __builtin_amdgcn_mfma_f32_16x16x32_bf16(af10, bfB[2], acc1, 0, 0, 0);
            acc0 = __builtin_amdgcn_mfma_f32_16x16x32_bf16(af01, bfB[3], acc0, 0, 0, 0);
            acc1 = __builtin_amdgcn_mfma_f32_16x16x32_bf16(af11, bfB[3], acc1, 0, 0, 0);
            acc0 = __builtin_amdgcn_mfma_f32_16x16x32_bf16(af02, bfB[4], acc0, 0, 0, 0);
            acc1 = __builtin_amdgcn_mfma_f32_16x16x32_bf16(af12, bfB[4], acc1, 0, 0, 0);
            acc0 = __builtin_amdgcn_mfma_f32_16x16x32_bf16(af03, bfB[5], acc0, 0, 0, 0);
            acc1 = __builtin_amdgcn_mfma_f32_16x16x32_bf16(af13, bfB[5], acc1, 0, 0, 0);
            int kcol = (nt + 1) * 16 + ln15;
#pragma unroll
            for (int r = 0; r < 4; ++r) {
                float d0 = cnB - 2.f * acc0[r];
                if (d0 < bd0[r]) { bd0[r] = d0; bk0[r] = kcol; }
                float d1 = cnB - 2.f * acc1[r];
                if (d1 < bd1[r]) { bd1[r] = d1; bk1[r] = kcol; }
            }
        }
    }
#pragma unroll
    for (int off = 1; off < 16; off <<= 1) {
#pragma unroll
        for (int r = 0; r < 4; ++r) {
            float od = __shfl_xor(bd0[r], off);
            int ok = __shfl_xor(bk0[r], off);
            if (od < bd0[r] || (od == bd0[r] && ok < bk0[r])) { bd0[r] = od; bk0[r] = ok; }
            od = __shfl_xor(bd1[r], off);
            ok = __shfl_xor(bk1[r], off);
            if (od < bd1[r] || (od == bd1[r] && ok < bk1[r])) { bd1[r] = od; bk1[r] = ok; }
        }
    }
    if ((lane & 15) == 0) {
#pragma unroll
        for (int r = 0; r < 4; ++r) {
            bkf[wave * 32 + (lane >> 4) * 4 + r] = bk0[r];
            bkf[wave * 32 + 16 + (lane >> 4) * 4 + r] = bk1[r];
        }
    }
    __syncthreads();
    float lsum = 0.f;
#pragma unroll
    for (int it = 0; it < 8; ++it) {
        int L = it * 256 + tid;
        int m = L >> 4, c4 = L & 15;
        int pix = blk * 128 + m;
        if (pix < npix) {
            int k0 = bkf[m];
            float4 cq = ((const float4*)cb)[(size_t)k0 * 16 + c4];
            const short* rz = a_lds + m * 136 + c4 * 4;
            s4v zh4 = *(const s4v*)rz;
            s4v zl4 = *(const s4v*)(rz + 64);
            float zx = bf2f((unsigned short)zh4[0]) + bf2f((unsigned short)zl4[0]);
            float zy = bf2f((unsigned short)zh4[1]) + bf2f((unsigned short)zl4[1]);
            float zz = bf2f((unsigned short)zh4[2]) + bf2f((unsigned short)zl4[2]);
            float zw = bf2f((unsigned short)zh4[3]) + bf2f((unsigned short)zl4[3]);
            float dx = cq.x - zx, dy = cq.y - zy, dz = cq.z - zz, dw = cq.w - zw;
            lsum += dx * dx + dy * dy + dz * dz + dw * dw;
            s4v qs;
            qs[0] = (short)f2bf(cq.x); qs[1] = (short)f2bf(cq.y);
            qs[2] = (short)f2bf(cq.z); qs[3] = (short)f2bf(cq.w);
            *(s4v*)(q + (size_t)pix * 64 + c4 * 4) = qs;
        }
    }
#pragma unroll
    for (int off = 32; off > 0; off >>= 1) lsum += __shfl_down(lsum, off);
    if (lane == 0) lred4[wave] = lsum;
    __syncthreads();
    if (tid == 0) lpart[blk] = lred4[0] + lred4[1] + lred4[2] + lred4[3];
}

// ---- k_loss: reduce lpart (<=1360 floats) -> single atomic -----------------
__global__ __launch_bounds__(256) void k_loss(const float* __restrict__ lpart,
                                              int nblk, float* __restrict__ loss) {
    int tid = threadIdx.x;
    float s = 0.f;
    for (int i = tid; i < nblk; i += 256) s += lpart[i];
#pragma unroll
    for (int off = 32; off > 0; off >>= 1) s += __shfl_down(s, off);
    __shared__ float w4[4];
    if ((tid & 63) == 0) w4[tid >> 6] = s;
    __syncthreads();
    if (tid == 0)
        atomicAdd(loss, (w4[0] + w4[1] + w4[2] + w4[3]) * (1.25f / 11075584.f));
}

// ---- tconv1 MFMA: q bf16 -> d1 bf16 (25,25,64), relu. 2 quad-rows/block ----
__global__ __launch_bounds__(256, 4) void k_tconv1_m(const unsigned short* __restrict__ q,
                                                     const unsigned short* __restrict__ wB,
                                                     const float* __restrict__ bias,
                                                     unsigned short* __restrict__ d1) {
    __shared__ short a_t[3 * 14 * 72];
    __shared__ short c_lds[32 * 264];
    int tid = threadIdx.x;
    int b = blockIdx.x, img = blockIdx.y;
#pragma unroll
    for (int pass = 0; pass < 2; ++pass) {
        int u = tid + pass * 256;            // [r3][c16][part8] = 384
        if (u < 384) {
            int px = u >> 3, part = u & 7;
            int r = px >> 4, c = px & 15;
            if (c < 14) {
                i4v v = (i4v){0, 0, 0, 0};
                int grow = 2 * b + r;
                if (grow < 13 && c < 13)
                    v = *(const i4v*)(q + ((size_t)img * 169 + grow * 13 + c) * 64 + part * 8);
                *(i4v*)(a_t + (r * 14 + c) * 72 + part * 8) = v;
            }
        }
    }
    __syncthreads();
    int wave = tid >> 6, lane = tid & 63;
    int g8 = (lane >> 4) * 8;
    int qw = lane & 15;
    int qwc = (qw < 13) ? qw : 0;
    int base0 = qwc * 72;            // qr = 0
    int base1 = (14 + qwc) * 72;     // qr = 1
    f4v acc[2][4];
#pragma unroll
    for (int mt = 0; mt < 2; ++mt)
#pragma unroll
        for (int i = 0; i < 4; ++i) acc[mt][i] = (f4v){0.f, 0.f, 0.f, 0.f};
    float bv[4];
#pragma unroll
    for (int i = 0; i < 4; ++i) bv[i] = bias[((wave * 4 + i) * 16 + (lane & 15)) & 63];
#pragma unroll
    for (int kc = 0; kc < 8; ++kc) {
        int k0 = kc * 32 + g8;
        int p = k0 >> 6, ci0 = k0 & 63;
        int off = ((p >> 1) * 14 + (p & 1)) * 72 + ci0;
        s8v a0 = *(const s8v*)(a_t + base0 + off);
        s8v a1 = *(const s8v*)(a_t + base1 + off);
#pragma unroll
        for (int i = 0; i < 4; ++i) {
            int nt = wave * 4 + i;
            s8v bb = *(const s8v*)((const short*)wB + ((size_t)((nt * 8 + kc) * 64 + lane)) * 8);
            acc[0][i] = __builtin_amdgcn_mfma_f32_16x16x32_bf16(a0, bb, acc[0][i], 0, 0, 0);
            acc[1][i] = __builtin_amdgcn_mfma_f32_16x16x32_bf16(a1, bb, acc[1][i], 0, 0, 0);
        }
    }
#pragma unroll
    for (int mt = 0; mt < 2; ++mt)
#pragma unroll
        for (int i = 0; i < 4; ++i) {
            int n = (wave * 4 + i) * 16 + (lane & 15);
#pragma unroll
            for (int r2 = 0; r2 < 4; ++r2) {
                int m = mt * 16 + (lane >> 4) * 4 + r2;
                float v = fmaxf(acc[mt][i][r2] + bv[i], 0.f);
                c_lds[m * 264 + n] = (short)f2bf(v);
            }
        }
    __syncthreads();
#pragma unroll
    for (int pass = 0; pass < 4; ++pass) {
        int ch = tid + pass * 256;
        int m = ch >> 5, cpart = ch & 31;
        int qwO = m & 15, qr = m >> 4;
        if (qwO >= 13) continue;
        int qm = 2 * b + qr;
        if (qm >= 13) continue;
        int cls = cpart >> 3, co8 = (cpart & 7) * 8;
        int oh = 2 * qm + (cls >> 1), ow = 2 * qwO + (cls & 1);
        if (oh >= 25 || ow >= 25) continue;
        i4v val = *(i4v*)(c_lds + m * 264 + cls * 64 + co8);
        *(i4v*)(d1 + (((size_t)img * 25 + oh) * 25 + ow) * 64 + co8) = val;
    }
}

// ---- tconv2 MFMA: d1 bf16 -> d2 bf16 (50,50,32), relu. 2 quad-rows/block ---
__global__ __launch_bounds__(256, 4) void k_tconv2_m(const unsigned short* __restrict__ d1,
                                                     const unsigned short* __restrict__ wB,
                                                     const float* __restrict__ bias,
                                                     unsigned short* __restrict__ d2) {
    __shared__ short a_t[3 * 26 * 72];
    __shared__ short c_lds[64 * 136];
    int tid = threadIdx.x;
    int b = blockIdx.x, img = blockIdx.y;
#pragma unroll
    for (int pass = 0; pass < 3; ++pass) {
        int u = tid + pass * 256;            // [r3][c32][part8] = 768
        int px = u >> 3, part = u & 7;
        int r = px >> 5, c = px & 31;
        if (c < 26) {
            i4v v = (i4v){0, 0, 0, 0};
            int grow = 2 * b + r;
            if (grow < 25 && c < 25)
                v = *(const i4v*)(d1 + (((size_t)img * 25 + grow) * 25 + c) * 64 + part * 8);
            *(i4v*)(a_t + (r * 26 + c) * 72 + part * 8) = v;
        }
    }
    __syncthreads();
    int wave = tid >> 6, lane = tid & 63;
    int g8 = (lane >> 4) * 8;
    int qwA = lane & 15;                 // mt 0,2
    int qwB = 16 + (lane & 15);          // mt 1,3
    int qBc = (qwB < 25) ? qwB : 0;
    int base0 = qwA * 72;                // qr0, low half
    int base1 = qBc * 72;                // qr0, high half
    int base2 = (26 + qwA) * 72;         // qr1, low half
    int base3 = (26 + qBc) * 72;         // qr1, high half
    f4v acc[4][2];
#pragma unroll
    for (int mt = 0; mt < 4; ++mt)
#pragma unroll
        for (int i = 0; i < 2; ++i) acc[mt][i] = (f4v){0.f, 0.f, 0.f, 0.f};
    float bv[2];
#pragma unroll
    for (int i = 0; i < 2; ++i) bv[i] = bias[((wave * 2 + i) * 16 + (lane & 15)) & 31];
#pragma unroll
    for (int kc = 0; kc < 8; ++kc) {
        int k0 = kc * 32 + g8;
        int p = k0 >> 6, ci0 = k0 & 63;
        int off = ((p >> 1) * 26 + (p & 1)) * 72 + ci0;
        s8v a0 = *(const s8v*)(a_t + base0 + off);
        s8v a1 = *(const s8v*)(a_t + base1 + off);
        s8v a2 = *(const s8v*)(a_t + base2 + off);
        s8v a3 = *(const s8v*)(a_t + base3 + off);
#pragma unroll
        for (int i = 0; i < 2; ++i) {
            int nt = wave * 2 + i;
            s8v bb = *(const s8v*)((const short*)wB + ((size_t)((nt * 8 + kc) * 64 + lane)) * 8);
            acc[0][i] = __builtin_amdgcn_mfma_f32_16x16x32_bf16(a0, bb, acc[0][i], 0, 0, 0);
            acc[1][i] = __builtin_amdgcn_mfma_f32_16x16x32_bf16(a1, bb, acc[1][i], 0, 0, 0);
            acc[2][i] = __builtin_amdgcn_mfma_f32_16x16x32_bf16(a2, bb, acc[2][i], 0, 0, 0);
            acc[3][i] = __builtin_amdgcn_mfma_f32_16x16x32_bf16(a3, bb, acc[3][i], 0, 0, 0);
        }
    }
#pragma unroll
    for (int mt = 0; mt < 4; ++mt)
#pragma unroll
        for (int i = 0; i < 2; ++i) {
            int n = (wave * 2 + i) * 16 + (lane & 15);
#pragma unroll
            for (int r2 = 0; r2 < 4; ++r2) {
                int m = mt * 16 + (lane >> 4) * 4 + r2;
                float v = fmaxf(acc[mt][i][r2] + bv[i], 0.f);
                c_lds[m * 136 + n] = (short)f2bf(v);
            }
        }
    __syncthreads();
#pragma unroll
    for (int pass = 0; pass < 4; ++pass) {
        int ch = tid + pass * 256;
        int m = ch >> 4, cpart = ch & 15;
        int qwO = m & 31, qr = m >> 5;
        if (qwO >= 25) continue;
        int qm = 2 * b + qr;
        if (qm >= 25) continue;
        int cls = cpart >> 2, co8 = (cpart & 3) * 8;
        int oh = 2 * qm + (cls >> 1), ow = 2 * qwO + (cls & 1);
        i4v val = *(i4v*)(c_lds + m * 136 + cls * 32 + co8);
        *(i4v*)(d2 + (((size_t)img * 50 + oh) * 50 + ow) * 32 + co8) = val;
    }
}

// ---- convf: LDS-staged strip, 512 thr, 1 output row/thread -----------------
// grid (5, bc); stage 12 clipped rows once -> LDS [12][50][36]sh; thread
// t<500 -> (orow=t/50, col=t%50) output row r0+orow; guard-free 3x3 taps.
__global__ __launch_bounds__(512, 2) void k_convf(const unsigned short* __restrict__ in,
                                                  const f2v* __restrict__ wpk,
                                                  const float* __restrict__ b,
                                                  float* __restrict__ out) {
    __shared__ short lds[12 * 50 * 36];   // 43200 B
    int strip = blockIdx.x, img = blockIdx.y;
    int r0 = strip * 10;
    int tid = threadIdx.x;
    // stage rows r0-1 .. r0+10 (12 rows; OOB rows zeroed) — 2400 i4v slots
#pragma unroll
    for (int pass = 0; pass < 5; ++pass) {
        int u = tid + pass * 512;
        if (u < 2400) {
            int px = u >> 2, chunk = u & 3;
            int row = px / 50, col = px - row * 50;
            int gr = r0 - 1 + row;
            i4v v = (i4v){0, 0, 0, 0};
            if ((unsigned)gr < 50u)
                v = *(const i4v*)(in + (((size_t)img * 50 + gr) * 50 + col) * 32 + chunk * 8);
            *(i4v*)(lds + (row * 50 + col) * 36 + chunk * 8) = v;
        }
    }
    __syncthreads();
    if (tid >= 500) return;
    int orow = tid / 50, col = tid - orow * 50;   // output row r0 + orow
    int lbase = orow;                             // LDS rows orow..orow+2
    f2v acc = (f2v){0.f, 0.f};
    for (int dx = -1; dx <= 1; ++dx) {
        int ic = col + dx;
        if ((unsigned)ic >= 50u) continue;
        int kw = dx + 1;
        const f2v* wp = wpk + kw * 48;
        f2v w2r[3][16];
#pragma unroll
        for (int kh = 0; kh < 3; ++kh)
#pragma unroll
            for (int i = 0; i < 16; ++i) w2r[kh][i] = wp[kh * 16 + i];
#pragma unroll
        for (int lr = 0; lr < 3; ++lr) {
            const short* px = lds + ((lbase + lr) * 50 + ic) * 36;
#pragma unroll
            for (int c8 = 0; c8 < 4; ++c8) {
                i4v u = *(const i4v*)(px + c8 * 8);
#pragma unroll
                for (int e = 0; e < 4; ++e) {
                    unsigned uu = (unsigned)u[e];
                    f2v x;
                    x[0] = __builtin_bit_cast(float, uu << 16);
                    x[1] = __builtin_bit_cast(float, uu & 0xffff0000u);
                    int i = c8 * 4 + e;
                    acc += x * w2r[lr][i];   // LDS row lbase+lr = tap kh=lr
                }
            }
        }
    }
    float b0 = b[0];
    float v = acc[0] + acc[1] + b0;
    out[(size_t)img * 2500 + (size_t)(r0 + orow) * 50 + col] = 1.f / (1.f + expf(-v));
}

extern "C" void kernel_launch(void* const* d_in, const int* in_sizes, int n_in,
                              void* d_out, int out_size, void* d_ws, size_t ws_size,
                              hipStream_t stream) {
    const float* x   = (const float*)d_in[0];
    const float* ew1 = (const float*)d_in[1];
    const float* eb1 = (const float*)d_in[2];
    const float* ew2 = (const float*)d_in[3];
    const float* eb2 = (const float*)d_in[4];
    const float* ew3 = (const float*)d_in[5];
    const float* eb3 = (const float*)d_in[6];
    const float* cb  = (const float*)d_in[7];
    const float* dw1 = (const float*)d_in[8];
    const float* db1 = (const float*)d_in[9];
    const float* dw2 = (const float*)d_in[10];
    const float* db2 = (const float*)d_in[11];
    const float* dw3 = (const float*)d_in[12];
    const float* db3 = (const float*)d_in[13];
    float* out = (float*)d_out;
    float* loss = out + 2560000;

    float* ws = (float*)d_ws;
    float* cn = ws;                                        // 512 f
    unsigned short* wB1  = (unsigned short*)(ws + 512);    // 65536 sh
    unsigned short* wB2  = (unsigned short*)(ws + 33280);  // 32768 sh
    unsigned short* wB2n = (unsigned short*)(ws + 49664);  // 55296 sh
    unsigned short* wB3  = (unsigned short*)(ws + 77312);  // 12288 sh
    unsigned short* cbm  = (unsigned short*)(ws + 83456);  // 98304 sh
    float* lpart = ws + 132608;                            // 1360 f
    f2v* wpk = (f2v*)(ws + 133968);                        // 144 f2v = 288 f
    const size_t tw_floats = 134256;

    const int B = 1024;
    const size_t A_per = 40000, B_per = 20000;
    size_t avail = (ws_size / 4 > tw_floats) ? ws_size / 4 - tw_floats : 0;
    int BC = (int)(avail / (A_per + B_per));
    if (BC > B) BC = B;
    if (BC < 1) BC = 1;
    float* regA = ws + tw_floats;
    float* regB = regA + (size_t)BC * A_per;

    k_prep_all<<<1035, 256, 0, stream>>>(cb, ew2, ew3, dw1, dw2, dw3,
                                         cbm, wB2n, wB1, wB2, wB3, cn, loss, wpk);

    for (int n0 = 0; n0 < B; n0 += BC) {
        int bc = (B - n0 < BC) ? (B - n0) : BC;
        const float* xch = x + (size_t)n0 * 2500;

        int t1 = bc * 625;   // conv1: x -> h1 split-bf16 (regA)
        unsigned short* h1p = (unsigned short*)regA;
        k_conv1<<<(t1 + 255) / 256, 256, 0, stream>>>(xch, ew1, eb1, h1p, t1);

        int npix = bc * 169;
        // fused conv2+conv3 MFMA (M=16): h1 (regA) -> z split-bf16 (regB)
        unsigned short* zp = (unsigned short*)regB;
        k_enc_m<<<(npix + 15) / 16, 256, 0, stream>>>(h1p, wB2n, wB3, eb2, eb3, zp, npix);

        // MFMA VQ (M=128, wave-local argmin): z (regB) -> q bf16 (regA) + lpart
        unsigned short* qb = (unsigned short*)regA;
        int nblk = (npix + 127) / 128;
        k_vq_m<<<nblk, 256, 0, stream>>>(zp, cb, cbm, cn, qb, lpart, npix);

        // loss partial reduce (1 block, 1 atomic)
        k_loss<<<1, 256, 0, stream>>>(lpart, nblk, loss);

        // tconv1 MFMA: q (regA bf16) -> d1 (regB bf16); grid (7, bc)
        unsigned short* d1 = (unsigned short*)regB;
        k_tconv1_m<<<dim3(7, bc), 256, 0, stream>>>(qb, wB1, db1, d1);

        // tconv2 MFMA: d1 (regB bf16) -> d2 (regA bf16); grid (13, bc)
        unsigned short* d2 = (unsigned short*)regA;
        k_tconv2_m<<<dim3(13, bc), 256, 0, stream>>>(d1, wB2, db2, d2);

        // convf: LDS-staged strips, 512 thr, grid (5, bc), d2 (regA) -> out
        k_convf<<<dim3(5, bc), 512, 0, stream>>>(d2, wpk, db3, out + (size_t)n0 * 2500);
    }
}

// Round 17
// 432.909 us; speedup vs baseline: 1.1915x; 1.1915x over previous
//
#include <hip/hip_runtime.h>
#include <math.h>

// ---------------------------------------------------------------------------
// VQ-VAE forward. R30 = revert convf to R25's proven form (best-known config;
// measured 434.3us total, convf 78.5us).
//  Convf ledger: R25 simple strips 78.5us; R26 channel-split 444 (spill);
//  R27 5-row 114.7 (halo); R28 LDS-staged 125.6 (30% occ latency);
//  R29 LDS+512thr 166 (staging-latency). Simple version wins: L2-thrash
//  traffic paid with enough in-flight loads to hide latency.
//  conv1: x -> h1 split-bf16 (n,25,25,[hi32|lo32])   [regA]
//  enc_m: h1 -> z split-bf16 (n,13,13,[zh64|zl64])   [regB]
//  vq_m:  z -> q bf16 [regA] + lpart (no atomics)
//  tconv1 MFMA: q -> d1 (n,25,25,64) bf16            [regB]
//  tconv2 MFMA: d1 -> d2 (n,50,50,32) bf16           [regA]
//  convf block=1img 10-row strips k3s1p1+sigm -> out (n,50,50)
// ---------------------------------------------------------------------------

typedef __attribute__((ext_vector_type(8))) short s8v;   // 8 bf16 frag
typedef __attribute__((ext_vector_type(4))) float f4v;   // MFMA acc
typedef __attribute__((ext_vector_type(4))) int i4v;
typedef __attribute__((ext_vector_type(4))) short s4v;
typedef __attribute__((ext_vector_type(2))) float f2v;   // packed f32 pair

__device__ inline unsigned short f2bf(float f) {  // RNE fp32->bf16
    unsigned u = __builtin_bit_cast(unsigned, f);
    return (unsigned short)((u + 0x7fffu + ((u >> 16) & 1u)) >> 16);
}
__device__ inline float bf2f(unsigned short h) {
    return __builtin_bit_cast(float, ((unsigned)h) << 16);
}

// ---- fused prep: cbm | B2n | B1 | B2 | B3 | cn | loss-zero | wpk -----------
__global__ __launch_bounds__(256) void k_prep_all(
        const float* __restrict__ cb,  const float* __restrict__ ew2,
        const float* __restrict__ ew3, const float* __restrict__ dw1,
        const float* __restrict__ dw2, const float* __restrict__ dw3,
        unsigned short* __restrict__ cbm, unsigned short* __restrict__ wB2n,
        unsigned short* __restrict__ wB1, unsigned short* __restrict__ wB2,
        unsigned short* __restrict__ wB3, float* __restrict__ cn,
        float* __restrict__ loss, f2v* __restrict__ wpk) {
    int i = blockIdx.x * 256 + threadIdx.x;
    if (i < 98304) {
        // cbm: VQ codebook 3-product split (nt32, kc6, lane64, j8)
        int j = i & 7, lane = (i >> 3) & 63;
        int kc = (i >> 9) % 6, nt = (i >> 9) / 6;
        int n = nt * 16 + (lane & 15);
        int k = kc * 32 + ((lane >> 4) << 3) + j;
        int seg = k >> 6, kk = k & 63;
        float c = cb[n * 64 + kk];
        unsigned short ch = f2bf(c);
        cbm[i] = (seg == 1) ? f2bf(c - bf2f(ch)) : ch;
    } else if (i < 153600) {
        // B2n: conv2 split (nt4, kc27, lane64, j8); K1=864 = [hi288|lo288|hi288]
        int q = i - 98304;
        int j = q & 7, lane = (q >> 3) & 63;
        int kc = (q >> 9) % 27, nt = (q >> 9) / 27;
        int k = kc * 32 + ((lane >> 4) << 3) + j;
        int co = nt * 16 + (lane & 15);
        int part = (k < 288) ? 0 : (k < 576) ? 1 : 0;
        int kk = (k < 288) ? k : (k < 576) ? k - 288 : k - 576;
        int tap = kk >> 5, ci = kk & 31;
        float v = ew2[(co * 32 + ci) * 9 + tap];
        unsigned short hi = f2bf(v);
        wB2n[q] = part ? f2bf(v - bf2f(hi)) : hi;
    } else if (i < 219136) {
        // B1: tconv1 zero-padded (nt16, kc8, lane64, j8)
        int q = i - 153600;
        int j = q & 7, l = (q >> 3) & 63, kc = (q >> 9) & 7, nt = q >> 12;
        int n = nt * 16 + (l & 15), k = kc * 32 + (l >> 4) * 8 + j;
        int cls = n >> 6, co = n & 63, p = k >> 6, ci = k & 63;
        int jh = -1, jw = -1;
        if (cls == 0)      { if (p == 0) { jh = 1; jw = 1; } }
        else if (cls == 1) { if (p == 1) { jh = 1; jw = 0; } else if (p == 0) { jh = 1; jw = 2; } }
        else if (cls == 2) { if (p == 2) { jh = 0; jw = 1; } else if (p == 0) { jh = 2; jw = 1; } }
        else { if (p == 3) { jh = 0; jw = 0; } else if (p == 2) { jh = 0; jw = 2; }
               else if (p == 1) { jh = 2; jw = 0; } else { jh = 2; jw = 2; } }
        float v = (jh >= 0) ? dw1[((co * 64 + ci) * 3 + jh) * 3 + jw] : 0.f;
        wB1[q] = f2bf(v);
    } else if (i < 251904) {
        // B2: tconv2 zero-padded (nt8, kc8, lane64, j8)
        int q = i - 219136;
        int j = q & 7, l = (q >> 3) & 63, kc = (q >> 9) & 7, nt = q >> 12;
        int n = nt * 16 + (l & 15), k = kc * 32 + (l >> 4) * 8 + j;
        int cls = n >> 5, co = n & 31, p = k >> 6, ci = k & 63;
        int jh = -1, jw = -1;
        if (cls == 0)      { if (p == 0) { jh = 1; jw = 1; } }
        else if (cls == 1) { if (p == 1) { jh = 1; jw = 0; } else if (p == 0) { jh = 1; jw = 2; } }
        else if (cls == 2) { if (p == 2) { jh = 0; jw = 1; } else if (p == 0) { jh = 2; jw = 1; } }
        else { if (p == 3) { jh = 0; jw = 0; } else if (p == 2) { jh = 0; jw = 2; }
               else if (p == 1) { jh = 2; jw = 0; } else { jh = 2; jw = 2; } }
        float v = (jh >= 0) ? dw2[((co * 64 + ci) * 3 + jh) * 3 + jw] : 0.f;
        wB2[q] = f2bf(v);
    } else if (i < 264192) {
        // B3: conv3 split (nt4, kc6, lane64, j8); K2=192 = [hi64|lo64|hi64]
        int q = i - 251904;
        int j = q & 7, lane = (q >> 3) & 63;
        int kc = (q >> 9) % 6, nt = (q >> 9) / 6;
        int k = kc * 32 + ((lane >> 4) << 3) + j;
        int n = nt * 16 + (lane & 15);
        int part = (k < 64) ? 0 : (k < 128) ? 1 : 0;
        int kk = (k < 64) ? k : (k < 128) ? k - 64 : k - 128;
        float v = ew3[n * 64 + kk];
        unsigned short hi = f2bf(v);
        wB3[q] = part ? f2bf(v - bf2f(hi)) : hi;
    } else if (i < 264704) {
        int k = i - 264192;
        const float* r = cb + k * 64;
        float s = 0.f;
#pragma unroll
        for (int c = 0; c < 64; ++c) s += r[c] * r[c];
        cn[k] = s;
    } else if (i == 264704) {
        *loss = 0.f;
    } else if (i < 264849) {
        // wpk: convf weights packed per channel-pair: wpk[(kw*3+kh)*16+ii]
        int q = i - 264705;
        int kw = q / 48, rem = q % 48, kh = rem / 16, ii = rem % 16;
        f2v w;
        w[0] = dw3[(2 * ii) * 9 + kh * 3 + kw];
        w[1] = dw3[(2 * ii + 1) * 9 + kh * 3 + kw];
        wpk[q] = w;
    }
}

// ---- conv1: x (bc,50,50) -> h1 split-bf16 (bc,25,25,[hi32|lo32]), relu -----
__global__ __launch_bounds__(256) void k_conv1(const float* __restrict__ x,
                                               const float* __restrict__ w,
                                               const float* __restrict__ b,
                                               unsigned short* __restrict__ h1,
                                               int total) {
    __shared__ float4 wl4[72];
    float* wl = (float*)wl4;
    int tid = threadIdx.x;
    for (int t = tid; t < 288; t += 256) {
        int tap = t >> 5, co = t & 31;
        wl[t] = w[co * 9 + tap];
    }
    __syncthreads();
    int pix = blockIdx.x * 256 + tid;
    if (pix >= total) return;
    int n = pix / 625, p = pix % 625, oh = p / 25, ow = p % 25;
    const float* xp = x + (size_t)n * 2500;
    float4 a[8];
#pragma unroll
    for (int j = 0; j < 8; ++j) a[j] = ((const float4*)b)[j];
#pragma unroll
    for (int kh = 0; kh < 3; ++kh) {
        int ih = 2 * oh - 1 + kh;
        if ((unsigned)ih >= 50u) continue;
#pragma unroll
        for (int kw = 0; kw < 3; ++kw) {
            int iw = 2 * ow - 1 + kw;
            if ((unsigned)iw >= 50u) continue;
            float v = xp[ih * 50 + iw];
            int tap = kh * 3 + kw;
#pragma unroll
            for (int j = 0; j < 8; ++j) {
                float4 ww = wl4[tap * 8 + j];
                a[j].x += v * ww.x; a[j].y += v * ww.y;
                a[j].z += v * ww.z; a[j].w += v * ww.w;
            }
        }
    }
    // relu + split-pack: [hi 32ch | lo 32ch] = 128 B/pixel (same bytes as f32)
    unsigned short hi[32], lo[32];
#pragma unroll
    for (int j = 0; j < 8; ++j) {
        float vv[4] = {a[j].x, a[j].y, a[j].z, a[j].w};
#pragma unroll
        for (int e = 0; e < 4; ++e) {
            float v = fmaxf(vv[e], 0.f);
            unsigned short h = f2bf(v);
            hi[j * 4 + e] = h;
            lo[j * 4 + e] = f2bf(v - bf2f(h));
        }
    }
    i4v* op = (i4v*)(h1 + (size_t)pix * 64);
#pragma unroll
    for (int g = 0; g < 4; ++g) {
        i4v ph, pl;
#pragma unroll
        for (int e = 0; e < 4; ++e) {
            int b0 = g * 8 + e * 2;
            ph[e] = (int)((unsigned)hi[b0] | ((unsigned)hi[b0 + 1] << 16));
            pl[e] = (int)((unsigned)lo[b0] | ((unsigned)lo[b0 + 1] << 16));
        }
        op[g] = ph;
        op[4 + g] = pl;
    }
}

// ---- enc_m: fused conv2(k3s2p1)+relu+conv3(1x1), split-bf16 MFMA (M=16) ----
// a1 deduped [hi 9x40 | lo 9x40] (row 728); A-frags register-resident.
__global__ __launch_bounds__(256, 2) void k_enc_m(const unsigned short* __restrict__ h1,
                                                  const unsigned short* __restrict__ B2n,
                                                  const unsigned short* __restrict__ B3,
                                                  const float* __restrict__ b2,
                                                  const float* __restrict__ b3,
                                                  unsigned short* __restrict__ z, int npix) {
    __shared__ short a1[16 * 728];   // [m16][seg2: hi|lo][tap9][40(32+8pad)]
    __shared__ short a2[16 * 136];   // [m16][zh64|zl64|pad8]
    __shared__ short czs[16 * 136];
    int tid = threadIdx.x, blk = blockIdx.x;
    // staging: u = (m*18 + (seg*9+t))*4 + sub; consecutive lanes ->
    // consecutive 16B LDS writes (conflict-free). 1152 slots, 5 passes.
#pragma unroll
    for (int pass = 0; pass < 5; ++pass) {
        int u = tid + pass * 256;
        if (u < 1152) {
            int m = u / 72, rem = u - m * 72;
            int idx = rem >> 2, sub = rem & 3;
            int seg = (idx >= 9) ? 1 : 0;
            int t = idx - seg * 9;
            i4v v = (i4v){0, 0, 0, 0};
            int pix = blk * 16 + m;
            if (pix < npix) {
                int n = pix / 169, p = pix % 169, oh = p / 13, ow = p % 13;
                int ih = 2 * oh - 1 + t / 3, iw = 2 * ow - 1 + t % 3;
                if (((unsigned)ih < 25u) && ((unsigned)iw < 25u))
                    v = *(const i4v*)(h1 + (((size_t)n * 25 + ih) * 25 + iw) * 64
                                      + (seg * 4 + sub) * 8);
            }
            *(i4v*)(a1 + m * 728 + seg * 360 + t * 40 + sub * 8) = v;
        }
    }
    __syncthreads();
    int wave = tid >> 6, lane = tid & 63;
    int r = lane & 15, g = lane >> 4;
    // A-fragments register-resident: 9 hi + 9 lo (72 VGPR)
    int abase = r * 728 + g * 8;
    s8v ah[9], al[9];
#pragma unroll
    for (int t = 0; t < 9; ++t) {
        ah[t] = *(const s8v*)(a1 + abase + t * 40);
        al[t] = *(const s8v*)(a1 + abase + 360 + t * 40);
    }
    f4v acc = (f4v){0.f, 0.f, 0.f, 0.f};
    // K=864 = [ah x wh (taps 0-8) | ah x wl | al x wh]
#pragma unroll
    for (int kc = 0; kc < 27; ++kc) {
        s8v b = *(const s8v*)((const short*)B2n + ((size_t)((wave * 27 + kc) * 64 + lane)) * 8);
        s8v a = (kc < 9) ? ah[kc] : (kc < 18) ? ah[kc - 9] : al[kc - 18];
        acc = __builtin_amdgcn_mfma_f32_16x16x32_bf16(a, b, acc, 0, 0, 0);
    }
    {
        float bv = b2[wave * 16 + r];
        int n = wave * 16 + r;
#pragma unroll
        for (int rr = 0; rr < 4; ++rr) {
            int m = g * 4 + rr;
            float h = fmaxf(acc[rr] + bv, 0.f);
            unsigned short hh = f2bf(h);
            a2[m * 136 + n] = (short)hh;
            a2[m * 136 + 64 + n] = (short)f2bf(h - bf2f(hh));
        }
    }
    __syncthreads();
    // conv3: 4 reg frags feed 6 MFMAs; B3 = [ch|cl|ch], A = [zh|zh|zl]
    int arow2 = r * 136 + g * 8;
    s8v zh0 = *(const s8v*)(a2 + arow2);
    s8v zh1 = *(const s8v*)(a2 + arow2 + 32);
    s8v zl0 = *(const s8v*)(a2 + arow2 + 64);
    s8v zl1 = *(const s8v*)(a2 + arow2 + 96);
    f4v acc2 = (f4v){0.f, 0.f, 0.f, 0.f};
    {
        const short* bp3 = (const short*)B3 + ((size_t)(wave * 6 * 64 + lane)) * 8;
        s8v b0 = *(const s8v*)(bp3);
        s8v b1 = *(const s8v*)(bp3 + 64 * 8);
        s8v b2f = *(const s8v*)(bp3 + 2 * 64 * 8);
        s8v b3f = *(const s8v*)(bp3 + 3 * 64 * 8);
        s8v b4 = *(const s8v*)(bp3 + 4 * 64 * 8);
        s8v b5 = *(const s8v*)(bp3 + 5 * 64 * 8);
        acc2 = __builtin_amdgcn_mfma_f32_16x16x32_bf16(zh0, b0, acc2, 0, 0, 0);
        acc2 = __builtin_amdgcn_mfma_f32_16x16x32_bf16(zh1, b1, acc2, 0, 0, 0);
        acc2 = __builtin_amdgcn_mfma_f32_16x16x32_bf16(zh0, b2f, acc2, 0, 0, 0);
        acc2 = __builtin_amdgcn_mfma_f32_16x16x32_bf16(zh1, b3f, acc2, 0, 0, 0);
        acc2 = __builtin_amdgcn_mfma_f32_16x16x32_bf16(zl0, b4, acc2, 0, 0, 0);
        acc2 = __builtin_amdgcn_mfma_f32_16x16x32_bf16(zl1, b5, acc2, 0, 0, 0);
    }
    {
        // emit z pre-split: [zh 64ch | zl 64ch] = 256 B/pixel (same bytes as f32)
        float bv = b3[wave * 16 + r];
        int n = wave * 16 + r;
#pragma unroll
        for (int rr = 0; rr < 4; ++rr) {
            int m = g * 4 + rr;
            float v = acc2[rr] + bv;
            unsigned short hh = f2bf(v);
            czs[m * 136 + n] = (short)hh;
            czs[m * 136 + 64 + n] = (short)f2bf(v - bf2f(hh));
        }
    }
    __syncthreads();
    {
        int m = tid >> 4, t = tid & 15;
        int pix = blk * 16 + m;
        if (pix < npix)
            *(i4v*)(z + (size_t)pix * 128 + t * 8) = *(i4v*)(czs + m * 136 + t * 8);
    }
}

// ---- vq_m: M=128/block, wave-local 512-code scan, loss partial store -------
__global__ __launch_bounds__(256, 2) void k_vq_m(const unsigned short* __restrict__ z,
                                                 const float* __restrict__ cb,
                                                 const unsigned short* __restrict__ cbm,
                                                 const float* __restrict__ cn,
                                                 unsigned short* __restrict__ q,
                                                 float* __restrict__ lpart, int npix) {
    __shared__ short a_lds[128 * 136];
    __shared__ int bkf[128];
    __shared__ float lred4[4];
    int tid = threadIdx.x, blk = blockIdx.x;
    {
        const i4v* src = (const i4v*)(z + (size_t)blk * 128 * 128);
#pragma unroll
        for (int it = 0; it < 8; ++it) {
            int L = it * 256 + tid;
            int m = L >> 4, s = L & 15;
            int pix = blk * 128 + m;
            i4v v = (i4v){0, 0, 0, 0};
            if (pix < npix) v = src[L];
            *(i4v*)(a_lds + m * 136 + s * 8) = v;
        }
    }
    __syncthreads();
    int wave = tid >> 6, lane = tid & 63;
    int arow0 = (wave * 32 + (lane & 15)) * 136 + (lane >> 4) * 8;
    int arow1 = arow0 + 16 * 136;
    s8v af00 = *(const s8v*)(a_lds + arow0);
    s8v af01 = *(const s8v*)(a_lds + arow0 + 32);
    s8v af02 = *(const s8v*)(a_lds + arow0 + 64);
    s8v af03 = *(const s8v*)(a_lds + arow0 + 96);
    s8v af10 = *(const s8v*)(a_lds + arow1);
    s8v af11 = *(const s8v*)(a_lds + arow1 + 32);
    s8v af12 = *(const s8v*)(a_lds + arow1 + 64);
    s8v af13 = *(const s8v*)(a_lds + arow1 + 96);
    float bd0[4], bd1[4];
    int bk0[4], bk1[4];
#pragma unroll
    for (int r = 0; r < 4; ++r) {
        bd0[r] = 3.4e38f; bk0[r] = 0;
        bd1[r] = 3.4e38f; bk1[r] = 0;
    }
    const s8v* bp = (const s8v*)cbm + lane;
    int ln15 = lane & 15;
    s8v bfA[6], bfB[6];
#pragma unroll
    for (int kc = 0; kc < 6; ++kc) bfA[kc] = bp[kc * 64];
    float cnA = cn[ln15];
    float cnB;
    for (int nt = 0; nt < 32; nt += 2) {
#pragma unroll
        for (int kc = 0; kc < 6; ++kc) bfB[kc] = bp[((nt + 1) * 6 + kc) * 64];
        cnB = cn[(nt + 1) * 16 + ln15];
        {
            f4v acc0 = (f4v){0.f, 0.f, 0.f, 0.f};
            f4v acc1 = (f4v){0.f, 0.f, 0.f, 0.f};
            acc0 = __builtin_amdgcn_mfma_f32_16x16x32_bf16(af00, bfA[0], acc0, 0, 0, 0);
            acc1 = __builtin_amdgcn_mfma_f32_16x16x32_bf16(af10, bfA[0], acc1, 0, 0, 0);
            acc0 = __builtin_amdgcn_mfma_f32_16x16x32_bf16(af01, bfA[1], acc0, 0, 0, 0);
            acc1 = __builtin_amdgcn_mfma_f32_16x16x32_bf16(af11, bfA[1], acc1, 0, 0, 0);
            acc0 = __builtin_amdgcn_mfma_f32_16x16x32_bf16(af00, bfA[2], acc0, 0, 0, 0);
            acc1 = __builtin_amdgcn_mfma_f32_16x16x32_bf16(af10, bfA[2], acc1, 0, 0, 0);
            acc0 = __builtin_amdgcn_mfma_f32_16x16x32_bf16(af01, bfA[3], acc0, 0, 0, 0);
            acc1 = __builtin_amdgcn_mfma_f32_16x16x32_bf16(af11, bfA[3], acc1, 0, 0, 0);
            acc0 = __builtin_amdgcn_mfma_f32_16x16x32_bf16(af02, bfA[4], acc0, 0, 0, 0);
            acc1 = __builtin_amdgcn_mfma_f32_16x16x32_bf16(af12, bfA[4], acc1, 0, 0, 0);
            acc0 = __builtin_amdgcn_mfma_f32_16x16x32_bf16(af03, bfA[5], acc0, 0, 0, 0);
            acc1 = __builtin_amdgcn_mfma_f32_16x16x32_bf16(af13, bfA[5], acc1, 0, 0, 0);
            int kcol = nt * 16 + ln15;
#pragma unroll
            for (int r = 0; r < 4; ++r) {
                float d0 = cnA - 2.f * acc0[r];
                if (d0 < bd0[r]) { bd0[r] = d0; bk0[r] = kcol; }
                float d1 = cnA - 2.f * acc1[r];
                if (d1 < bd1[r]) { bd1[r] = d1; bk1[r] = kcol; }
            }
        }
        if (nt + 2 < 32) {
#pragma unroll
            for (int kc = 0; kc < 6; ++kc) bfA[kc] = bp[((nt + 2) * 6 + kc) * 64];
            cnA = cn[(nt + 2) * 16 + ln15];
        }
        {
            f4v acc0 = (f4v){0.f, 0.f, 0.f, 0.f};
            f4v acc1 = (f4v){0.f, 0.f, 0.f, 0.f};
            acc0 = __builtin_amdgcn_mfma_f32_16x16x32_bf16(af00, bfB[0], acc0, 0, 0, 0);
            acc1 = __builtin_amdgcn_mfma_f32_16x16x32_bf16(af10, bfB[0], acc1, 0, 0, 0);
            acc0 = __builtin_amdgcn_mfma_f32_16x16x32_bf16(af01, bfB[1], acc0, 0, 0, 0);
            acc1 = __builtin_amdgcn_mfma_f32_16x16x32_bf16(af11, bfB[1], acc1, 0, 0, 0);
            acc0 = __builtin_amdgcn_mfma_f32_16x16x32_bf16(af00, bfB[2], acc0, 0, 0, 0);
            acc1 = __builtin_amdgcn_mfma_f32_16x16x32_bf16(af10, bfB[2], acc1, 0, 0, 0);
            acc0 = __builtin_amdgcn_mfma_f32_16x16x32_bf16(af01, bfB[3], acc0, 0, 0, 0);
            acc1 = __builtin_amdgcn_mfma_f32_16x16x32_bf16(af11, bfB[3], acc1, 0, 0, 0);
            acc0 = __builtin_amdgcn_mfma_f32_16x16x32_bf16(af02, bfB[4], acc0, 0, 0, 0);
            acc1 = __builtin_amdgcn_mfma_f32_16x16x32_bf16(af12, bfB[4], acc1, 0, 0, 0);
            acc0 = __builtin_amdgcn_mfma_f32_16x16x32_bf16(af03, bfB[5], acc0, 0, 0, 0);
            acc1 = __builtin_amdgcn_mfma_f32_16x16x32_bf16(af13, bfB[5], acc1, 0, 0, 0);
            int kcol = (nt + 1) * 16 + ln15;
#pragma unroll
            for (int r = 0; r < 4; ++r) {
                float d0 = cnB - 2.f * acc0[r];
                if (d0 < bd0[r]) { bd0[r] = d0; bk0[r] = kcol; }
                float d1 = cnB - 2.f * acc1[r];
                if (d1 < bd1[r]) { bd1[r] = d1; bk1[r] = kcol; }
            }
        }
    }
#pragma unroll
    for (int off = 1; off < 16; off <<= 1) {
#pragma unroll
        for (int r = 0; r < 4; ++r) {
            float od = __shfl_xor(bd0[r], off);
            int ok = __shfl_xor(bk0[r], off);
            if (od < bd0[r] || (od == bd0[r] && ok < bk0[r])) { bd0[r] = od; bk0[r] = ok; }
            od = __shfl_xor(bd1[r], off);
            ok = __shfl_xor(bk1[r], off);
            if (od < bd1[r] || (od == bd1[r] && ok < bk1[r])) { bd1[r] = od; bk1[r] = ok; }
        }
    }
    if ((lane & 15) == 0) {
#pragma unroll
        for (int r = 0; r < 4; ++r) {
            bkf[wave * 32 + (lane >> 4) * 4 + r] = bk0[r];
            bkf[wave * 32 + 16 + (lane >> 4) * 4 + r] = bk1[r];
        }
    }
    __syncthreads();
    float lsum = 0.f;
#pragma unroll
    for (int it = 0; it < 8; ++it) {
        int L = it * 256 + tid;
        int m = L >> 4, c4 = L & 15;
        int pix = blk * 128 + m;
        if (pix < npix) {
            int k0 = bkf[m];
            float4 cq = ((const float4*)cb)[(size_t)k0 * 16 + c4];
            const short* rz = a_lds + m * 136 + c4 * 4;
            s4v zh4 = *(const s4v*)rz;
            s4v zl4 = *(const s4v*)(rz + 64);
            float zx = bf2f((unsigned short)zh4[0]) + bf2f((unsigned short)zl4[0]);
            float zy = bf2f((unsigned short)zh4[1]) + bf2f((unsigned short)zl4[1]);
            float zz = bf2f((unsigned short)zh4[2]) + bf2f((unsigned short)zl4[2]);
            float zw = bf2f((unsigned short)zh4[3]) + bf2f((unsigned short)zl4[3]);
            float dx = cq.x - zx, dy = cq.y - zy, dz = cq.z - zz, dw = cq.w - zw;
            lsum += dx * dx + dy * dy + dz * dz + dw * dw;
            s4v qs;
            qs[0] = (short)f2bf(cq.x); qs[1] = (short)f2bf(cq.y);
            qs[2] = (short)f2bf(cq.z); qs[3] = (short)f2bf(cq.w);
            *(s4v*)(q + (size_t)pix * 64 + c4 * 4) = qs;
        }
    }
#pragma unroll
    for (int off = 32; off > 0; off >>= 1) lsum += __shfl_down(lsum, off);
    if (lane == 0) lred4[wave] = lsum;
    __syncthreads();
    if (tid == 0) lpart[blk] = lred4[0] + lred4[1] + lred4[2] + lred4[3];
}

// ---- k_loss: reduce lpart (<=1360 floats) -> single atomic -----------------
__global__ __launch_bounds__(256) void k_loss(const float* __restrict__ lpart,
                                              int nblk, float* __restrict__ loss) {
    int tid = threadIdx.x;
    float s = 0.f;
    for (int i = tid; i < nblk; i += 256) s += lpart[i];
#pragma unroll
    for (int off = 32; off > 0; off >>= 1) s += __shfl_down(s, off);
    __shared__ float w4[4];
    if ((tid & 63) == 0) w4[tid >> 6] = s;
    __syncthreads();
    if (tid == 0)
        atomicAdd(loss, (w4[0] + w4[1] + w4[2] + w4[3]) * (1.25f / 11075584.f));
}

// ---- tconv1 MFMA: q bf16 -> d1 bf16 (25,25,64), relu. 2 quad-rows/block ----
__global__ __launch_bounds__(256, 4) void k_tconv1_m(const unsigned short* __restrict__ q,
                                                     const unsigned short* __restrict__ wB,
                                                     const float* __restrict__ bias,
                                                     unsigned short* __restrict__ d1) {
    __shared__ short a_t[3 * 14 * 72];
    __shared__ short c_lds[32 * 264];
    int tid = threadIdx.x;
    int b = blockIdx.x, img = blockIdx.y;
#pragma unroll
    for (int pass = 0; pass < 2; ++pass) {
        int u = tid + pass * 256;            // [r3][c16][part8] = 384
        if (u < 384) {
            int px = u >> 3, part = u & 7;
            int r = px >> 4, c = px & 15;
            if (c < 14) {
                i4v v = (i4v){0, 0, 0, 0};
                int grow = 2 * b + r;
                if (grow < 13 && c < 13)
                    v = *(const i4v*)(q + ((size_t)img * 169 + grow * 13 + c) * 64 + part * 8);
                *(i4v*)(a_t + (r * 14 + c) * 72 + part * 8) = v;
            }
        }
    }
    __syncthreads();
    int wave = tid >> 6, lane = tid & 63;
    int g8 = (lane >> 4) * 8;
    int qw = lane & 15;
    int qwc = (qw < 13) ? qw : 0;
    int base0 = qwc * 72;            // qr = 0
    int base1 = (14 + qwc) * 72;     // qr = 1
    f4v acc[2][4];
#pragma unroll
    for (int mt = 0; mt < 2; ++mt)
#pragma unroll
        for (int i = 0; i < 4; ++i) acc[mt][i] = (f4v){0.f, 0.f, 0.f, 0.f};
    float bv[4];
#pragma unroll
    for (int i = 0; i < 4; ++i) bv[i] = bias[((wave * 4 + i) * 16 + (lane & 15)) & 63];
#pragma unroll
    for (int kc = 0; kc < 8; ++kc) {
        int k0 = kc * 32 + g8;
        int p = k0 >> 6, ci0 = k0 & 63;
        int off = ((p >> 1) * 14 + (p & 1)) * 72 + ci0;
        s8v a0 = *(const s8v*)(a_t + base0 + off);
        s8v a1 = *(const s8v*)(a_t + base1 + off);
#pragma unroll
        for (int i = 0; i < 4; ++i) {
            int nt = wave * 4 + i;
            s8v bb = *(const s8v*)((const short*)wB + ((size_t)((nt * 8 + kc) * 64 + lane)) * 8);
            acc[0][i] = __builtin_amdgcn_mfma_f32_16x16x32_bf16(a0, bb, acc[0][i], 0, 0, 0);
            acc[1][i] = __builtin_amdgcn_mfma_f32_16x16x32_bf16(a1, bb, acc[1][i], 0, 0, 0);
        }
    }
#pragma unroll
    for (int mt = 0; mt < 2; ++mt)
#pragma unroll
        for (int i = 0; i < 4; ++i) {
            int n = (wave * 4 + i) * 16 + (lane & 15);
#pragma unroll
            for (int r2 = 0; r2 < 4; ++r2) {
                int m = mt * 16 + (lane >> 4) * 4 + r2;
                float v = fmaxf(acc[mt][i][r2] + bv[i], 0.f);
                c_lds[m * 264 + n] = (short)f2bf(v);
            }
        }
    __syncthreads();
#pragma unroll
    for (int pass = 0; pass < 4; ++pass) {
        int ch = tid + pass * 256;
        int m = ch >> 5, cpart = ch & 31;
        int qwO = m & 15, qr = m >> 4;
        if (qwO >= 13) continue;
        int qm = 2 * b + qr;
        if (qm >= 13) continue;
        int cls = cpart >> 3, co8 = (cpart & 7) * 8;
        int oh = 2 * qm + (cls >> 1), ow = 2 * qwO + (cls & 1);
        if (oh >= 25 || ow >= 25) continue;
        i4v val = *(i4v*)(c_lds + m * 264 + cls * 64 + co8);
        *(i4v*)(d1 + (((size_t)img * 25 + oh) * 25 + ow) * 64 + co8) = val;
    }
}

// ---- tconv2 MFMA: d1 bf16 -> d2 bf16 (50,50,32), relu. 2 quad-rows/block ---
__global__ __launch_bounds__(256, 4) void k_tconv2_m(const unsigned short* __restrict__ d1,
                                                     const unsigned short* __restrict__ wB,
                                                     const float* __restrict__ bias,
                                                     unsigned short* __restrict__ d2) {
    __shared__ short a_t[3 * 26 * 72];
    __shared__ short c_lds[64 * 136];
    int tid = threadIdx.x;
    int b = blockIdx.x, img = blockIdx.y;
#pragma unroll
    for (int pass = 0; pass < 3; ++pass) {
        int u = tid + pass * 256;            // [r3][c32][part8] = 768
        int px = u >> 3, part = u & 7;
        int r = px >> 5, c = px & 31;
        if (c < 26) {
            i4v v = (i4v){0, 0, 0, 0};
            int grow = 2 * b + r;
            if (grow < 25 && c < 25)
                v = *(const i4v*)(d1 + (((size_t)img * 25 + grow) * 25 + c) * 64 + part * 8);
            *(i4v*)(a_t + (r * 26 + c) * 72 + part * 8) = v;
        }
    }
    __syncthreads();
    int wave = tid >> 6, lane = tid & 63;
    int g8 = (lane >> 4) * 8;
    int qwA = lane & 15;                 // mt 0,2
    int qwB = 16 + (lane & 15);          // mt 1,3
    int qBc = (qwB < 25) ? qwB : 0;
    int base0 = qwA * 72;                // qr0, low half
    int base1 = qBc * 72;                // qr0, high half
    int base2 = (26 + qwA) * 72;         // qr1, low half
    int base3 = (26 + qBc) * 72;         // qr1, high half
    f4v acc[4][2];
#pragma unroll
    for (int mt = 0; mt < 4; ++mt)
#pragma unroll
        for (int i = 0; i < 2; ++i) acc[mt][i] = (f4v){0.f, 0.f, 0.f, 0.f};
    float bv[2];
#pragma unroll
    for (int i = 0; i < 2; ++i) bv[i] = bias[((wave * 2 + i) * 16 + (lane & 15)) & 31];
#pragma unroll
    for (int kc = 0; kc < 8; ++kc) {
        int k0 = kc * 32 + g8;
        int p = k0 >> 6, ci0 = k0 & 63;
        int off = ((p >> 1) * 26 + (p & 1)) * 72 + ci0;
        s8v a0 = *(const s8v*)(a_t + base0 + off);
        s8v a1 = *(const s8v*)(a_t + base1 + off);
        s8v a2 = *(const s8v*)(a_t + base2 + off);
        s8v a3 = *(const s8v*)(a_t + base3 + off);
#pragma unroll
        for (int i = 0; i < 2; ++i) {
            int nt = wave * 2 + i;
            s8v bb = *(const s8v*)((const short*)wB + ((size_t)((nt * 8 + kc) * 64 + lane)) * 8);
            acc[0][i] = __builtin_amdgcn_mfma_f32_16x16x32_bf16(a0, bb, acc[0][i], 0, 0, 0);
            acc[1][i] = __builtin_amdgcn_mfma_f32_16x16x32_bf16(a1, bb, acc[1][i], 0, 0, 0);
            acc[2][i] = __builtin_amdgcn_mfma_f32_16x16x32_bf16(a2, bb, acc[2][i], 0, 0, 0);
            acc[3][i] = __builtin_amdgcn_mfma_f32_16x16x32_bf16(a3, bb, acc[3][i], 0, 0, 0);
        }
    }
#pragma unroll
    for (int mt = 0; mt < 4; ++mt)
#pragma unroll
        for (int i = 0; i < 2; ++i) {
            int n = (wave * 2 + i) * 16 + (lane & 15);
#pragma unroll
            for (int r2 = 0; r2 < 4; ++r2) {
                int m = mt * 16 + (lane >> 4) * 4 + r2;
                float v = fmaxf(acc[mt][i][r2] + bv[i], 0.f);
                c_lds[m * 136 + n] = (short)f2bf(v);
            }
        }
    __syncthreads();
#pragma unroll
    for (int pass = 0; pass < 4; ++pass) {
        int ch = tid + pass * 256;
        int m = ch >> 4, cpart = ch & 15;
        int qwO = m & 31, qr = m >> 5;
        if (qwO >= 25) continue;
        int qm = 2 * b + qr;
        if (qm >= 25) continue;
        int cls = cpart >> 2, co8 = (cpart & 3) * 8;
        int oh = 2 * qm + (cls >> 1), ow = 2 * qwO + (cls & 1);
        i4v val = *(i4v*)(c_lds + m * 136 + cls * 32 + co8);
        *(i4v*)(d2 + (((size_t)img * 50 + oh) * 50 + ow) * 32 + co8) = val;
    }
}

// ---- convf: block = 1 image (XCD-local), 250 threads: strip=t/50, col=t%50 -
// 10 outputs/thread, reg-resident packed weights (R25 proven form, 78.5us).
__global__ __launch_bounds__(256, 2) void k_convf(const unsigned short* __restrict__ in,
                                                  const f2v* __restrict__ wpk,
                                                  const float* __restrict__ b,
                                                  float* __restrict__ out) {
    int img = blockIdx.x;
    int t = threadIdx.x;
    if (t >= 250) return;
    int strip = t / 50, col = t % 50;
    int r0 = strip * 10;
    const unsigned short* base = in + (size_t)img * 80000;  // 50*50*32
    f2v acc[10];
#pragma unroll
    for (int i = 0; i < 10; ++i) acc[i] = (f2v){0.f, 0.f};
    for (int dx = -1; dx <= 1; ++dx) {
        int ic = col + dx;
        if ((unsigned)ic >= 50u) continue;
        int kw = dx + 1;
        const f2v* wp = wpk + kw * 48;
        f2v w2r[3][16];
#pragma unroll
        for (int kh = 0; kh < 3; ++kh)
#pragma unroll
            for (int i = 0; i < 16; ++i) w2r[kh][i] = wp[kh * 16 + i];
#pragma unroll
        for (int rr = -1; rr <= 10; ++rr) {
            int ih = r0 + rr;
            if ((unsigned)ih >= 50u) continue;
            const i4v* px = (const i4v*)(base + ((size_t)ih * 50 + ic) * 32);
#pragma unroll
            for (int c8 = 0; c8 < 4; ++c8) {
                i4v u = px[c8];
#pragma unroll
                for (int e = 0; e < 4; ++e) {
                    unsigned uu = (unsigned)u[e];
                    f2v x;
                    x[0] = __builtin_bit_cast(float, uu << 16);
                    x[1] = __builtin_bit_cast(float, uu & 0xffff0000u);
                    int i = c8 * 4 + e;
                    if (rr - 1 >= 0 && rr - 1 <= 9) acc[rr - 1] += x * w2r[2][i];
                    if (rr >= 0 && rr <= 9)         acc[rr]     += x * w2r[1][i];
                    if (rr + 1 >= 0 && rr + 1 <= 9) acc[rr + 1] += x * w2r[0][i];
                }
            }
        }
    }
    float b0 = b[0];
    float* op = out + (size_t)img * 2500 + (size_t)r0 * 50 + col;
#pragma unroll
    for (int i = 0; i < 10; ++i) {
        float v = acc[i][0] + acc[i][1] + b0;
        op[(size_t)i * 50] = 1.f / (1.f + expf(-v));
    }
}

extern "C" void kernel_launch(void* const* d_in, const int* in_sizes, int n_in,
                              void* d_out, int out_size, void* d_ws, size_t ws_size,
                              hipStream_t stream) {
    const float* x   = (const float*)d_in[0];
    const float* ew1 = (const float*)d_in[1];
    const float* eb1 = (const float*)d_in[2];
    const float* ew2 = (const float*)d_in[3];
    const float* eb2 = (const float*)d_in[4];
    const float* ew3 = (const float*)d_in[5];
    const float* eb3 = (const float*)d_in[6];
    const float* cb  = (const float*)d_in[7];
    const float* dw1 = (const float*)d_in[8];
    const float* db1 = (const float*)d_in[9];
    const float* dw2 = (const float*)d_in[10];
    const float* db2 = (const float*)d_in[11];
    const float* dw3 = (const float*)d_in[12];
    const float* db3 = (const float*)d_in[13];
    float* out = (float*)d_out;
    float* loss = out + 2560000;

    float* ws = (float*)d_ws;
    float* cn = ws;                                        // 512 f
    unsigned short* wB1  = (unsigned short*)(ws + 512);    // 65536 sh
    unsigned short* wB2  = (unsigned short*)(ws + 33280);  // 32768 sh
    unsigned short* wB2n = (unsigned short*)(ws + 49664);  // 55296 sh
    unsigned short* wB3  = (unsigned short*)(ws + 77312);  // 12288 sh
    unsigned short* cbm  = (unsigned short*)(ws + 83456);  // 98304 sh
    float* lpart = ws + 132608;                            // 1360 f
    f2v* wpk = (f2v*)(ws + 133968);                        // 144 f2v = 288 f
    const size_t tw_floats = 134256;

    const int B = 1024;
    const size_t A_per = 40000, B_per = 20000;
    size_t avail = (ws_size / 4 > tw_floats) ? ws_size / 4 - tw_floats : 0;
    int BC = (int)(avail / (A_per + B_per));
    if (BC > B) BC = B;
    if (BC < 1) BC = 1;
    float* regA = ws + tw_floats;
    float* regB = regA + (size_t)BC * A_per;

    k_prep_all<<<1035, 256, 0, stream>>>(cb, ew2, ew3, dw1, dw2, dw3,
                                         cbm, wB2n, wB1, wB2, wB3, cn, loss, wpk);

    for (int n0 = 0; n0 < B; n0 += BC) {
        int bc = (B - n0 < BC) ? (B - n0) : BC;
        const float* xch = x + (size_t)n0 * 2500;

        int t1 = bc * 625;   // conv1: x -> h1 split-bf16 (regA)
        unsigned short* h1p = (unsigned short*)regA;
        k_conv1<<<(t1 + 255) / 256, 256, 0, stream>>>(xch, ew1, eb1, h1p, t1);

        int npix = bc * 169;
        // fused conv2+conv3 MFMA (M=16): h1 (regA) -> z split-bf16 (regB)
        unsigned short* zp = (unsigned short*)regB;
        k_enc_m<<<(npix + 15) / 16, 256, 0, stream>>>(h1p, wB2n, wB3, eb2, eb3, zp, npix);

        // MFMA VQ (M=128, wave-local argmin): z (regB) -> q bf16 (regA) + lpart
        unsigned short* qb = (unsigned short*)regA;
        int nblk = (npix + 127) / 128;
        k_vq_m<<<nblk, 256, 0, stream>>>(zp, cb, cbm, cn, qb, lpart, npix);

        // loss partial reduce (1 block, 1 atomic)
        k_loss<<<1, 256, 0, stream>>>(lpart, nblk, loss);

        // tconv1 MFMA: q (regA bf16) -> d1 (regB bf16); grid (7, bc)
        unsigned short* d1 = (unsigned short*)regB;
        k_tconv1_m<<<dim3(7, bc), 256, 0, stream>>>(qb, wB1, db1, d1);

        // tconv2 MFMA: d1 (regB bf16) -> d2 (regA bf16); grid (13, bc)
        unsigned short* d2 = (unsigned short*)regA;
        k_tconv2_m<<<dim3(13, bc), 256, 0, stream>>>(d1, wB2, db2, d2);

        // convf: block = 1 image (XCD-local), d2 bf16 (regA) -> out
        k_convf<<<bc, 256, 0, stream>>>(d2, wpk, db3, out + (size_t)n0 * 2500);
    }
}